// Round 17
// baseline (275.788 us; speedup 1.0000x reference)
//
#include <hip/hip_runtime.h>
#include <math.h>

#define NN 16384
#define NE 65536
#define HH 128

// ---- constants matching the reference exactly (double, folded to f32) ----
constexpr double D_START = 0.011108996538242306;   // exp(-4.5)
constexpr double D_STEP  = (1.0 - D_START) / 31.0;
constexpr float  F_ALPHA = (float)(5.0/4.5);
constexpr double D_BB    = (2.0/32.0)*(1.0 - D_START);
constexpr float  F_BETA  = (float)(1.0/(D_BB*D_BB));
constexpr float  F_PIC   = (float)(M_PI/4.5);

// fallback scratch pool (used if ws_size too small). ~4 MB needed now.
#define POOL_BYTES (8u*1024u*1024u)
__device__ __align__(256) static char g_pool[POOL_BYTES];

typedef __attribute__((ext_vector_type(8))) short bf16x8;
typedef __attribute__((ext_vector_type(4))) float f32x4;

__device__ __forceinline__ float siluf(float x){
  return x * (1.0f/(1.0f + expf(-x)));
}
__device__ __forceinline__ short f2bf(float x){
  unsigned u = __float_as_uint(x);
  unsigned r = (u + 0x7fffu + ((u>>16)&1u)) >> 16;
  return (short)r;
}
__device__ __forceinline__ float bf2f(short h){
  return __uint_as_float(((unsigned)(unsigned short)h)<<16);
}
__device__ __forceinline__ void split_bf(float x, short& h, short& l){
  h = f2bf(x);
  l = f2bf(x - bf2f(h));
}

// =====================================================================
// PREP: one kernel, three independent block ranges:
//   [0,64)      : PZ/QZ tables (2 atom rows per block)
//   [64,1040)   : weight fp32 -> bf16 hi/lo conversion
//   [1040,1296) : edge distance filter -> bucket by 16-node group
// =====================================================================
__global__ __launch_bounds__(256) void k_prep(
    const int* __restrict__ ei, const float* __restrict__ pos,
    const float* __restrict__ emb_w, const float* __restrict__ emb2_w,
    const float* __restrict__ emb2_b,
    const float* __restrict__ ls0, const float* __restrict__ ls1,
    const float* __restrict__ lin, const float* __restrict__ lt0,
    const float* __restrict__ lt1, const float* __restrict__ lt2,
    const float* __restrict__ dp1, const float* __restrict__ dp2,
    const float* __restrict__ dp3, const float* __restrict__ ol1,
    float* __restrict__ PZ, float* __restrict__ QZ,
    int* __restrict__ bcnt, int* __restrict__ bucket,
    short* __restrict__ ls0h, short* __restrict__ ls0l,
    short* __restrict__ ls1h, short* __restrict__ ls1l,
    short* __restrict__ linh, short* __restrict__ linl,
    short* __restrict__ lt0h, short* __restrict__ lt0l,
    short* __restrict__ lt1h, short* __restrict__ lt1l,
    short* __restrict__ lt2h, short* __restrict__ lt2l,
    short* __restrict__ dwh, short* __restrict__ dwl,
    short* __restrict__ ol1h, short* __restrict__ ol1l){
  int b = blockIdx.x;
  if (b < 64){
    __shared__ float erow[2][128];
    int sub = threadIdx.x >> 7, h = threadIdx.x & 127;
    int a = b*2 + sub;
    erow[sub][h] = emb_w[a*128 + h];
    __syncthreads();
    float p = 0.f, q = 0.f;
    #pragma unroll 8
    for (int k=0;k<128;++k){
      float e = erow[sub][k];
      p += e * emb2_w[h*256 + k];
      q += e * emb2_w[h*256 + 128 + k];
    }
    PZ[a*128 + h] = p + emb2_b[h];
    QZ[a*128 + h] = q;
    return;
  }
  if (b < 1040){
    int tid = (b-64)*256 + threadIdx.x;   // 249856 total
    const float* s; short *dh, *dl; int i;
    if      (tid < 32768)  { s=ls0; dh=ls0h; dl=ls0l; i=tid; }
    else if (tid < 131072) { s=ls1; dh=ls1h; dl=ls1l; i=tid-32768; }
    else if (tid < 180224) { s=lin; dh=linh; dl=linl; i=tid-131072; }
    else if (tid < 196608) { s=lt0; dh=lt0h; dl=lt0l; i=tid-180224; }
    else if (tid < 212992) { s=lt1; dh=lt1h; dl=lt1l; i=tid-196608; }
    else if (tid < 229376) { s=lt2; dh=lt2h; dl=lt2l; i=tid-212992; }
    else if (tid < 241664) {
      int j = tid - 229376;       // [g*4096 + idx]
      int g = j >> 12, idx = j & 4095;
      s = (g==0)?dp1:((g==1)?dp2:dp3);
      short h,l; split_bf(s[idx], h, l);
      dwh[j] = h; dwl[j] = l;
      return;
    }
    else { s=ol1; dh=ol1h; dl=ol1l; i=tid-241664; }
    short h,l; split_bf(s[i], h, l);
    dh[i] = h; dl[i] = l;
    return;
  }
  {
    int e = (b-1040)*256 + threadIdx.x;
    int s = ei[e];
    int t = ei[NE + e];
    float dx = pos[3*s+0] - pos[3*t+0];
    float dy = pos[3*s+1] - pos[3*t+1];
    float dz = pos[3*s+2] - pos[3*t+2];
    float d = sqrtf(dx*dx + dy*dy + dz*dz);
    if (d < 4.5f){
      int g16 = s >> 4;
      int p = atomicAdd(&bcnt[g16], 1);
      if (p < 512) bucket[g16*512 + p] = (e<<4) | (s & 15);
    }
  }
}

// =====================================================================
// MEGA: 512 threads (8 waves), 16 nodes/block, fused RBF prologue,
// COMPACT 53248 B LDS arena -> 3 blocks/CU if actual regs (64 VGPR +
// ~20 AGPR, measured R15) fit 6 waves/SIMD (<=85). Targets the batch
// count: 1024 blocks / 768 resident = 1.33 batches (was 2).
// Region A [0, 28160): Dt[16][388]f32 (24832) + elocal(2048@24832) +
//                       counts(@26880) | T1 h/l (18432) | mix tile
//                       2pl x 4hc4 x 2560 B = 20480 B | xls f32 (24832) |
//                       X3 h/l (10240) + head partials (@10240)
// Region B [28160, 53248) = 25088 B: tmpb / chunk scratch | tnorm h/l
//                       (10240) | NRM f32 (24832) | xh/xl (25088 exactly)
// Mix = 5 passes x 2 planes (R13-verified barriers; tile max 20478 B < A).
// __launch_bounds__(512,4): cap 128, spill-free in R15 (VGPR 64).
// =====================================================================
__global__ __launch_bounds__(512, 4) void k_mega(
    const int* __restrict__ bcnt, const int* __restrict__ bucket,
    const int* __restrict__ ei, const float* __restrict__ pos,
    const int* __restrict__ zA,
    const short* __restrict__ dwh, const short* __restrict__ dwl,
    const float* __restrict__ db1, const float* __restrict__ db2,
    const float* __restrict__ db3,
    const float* __restrict__ PZ, const float* __restrict__ QZ,
    const float* __restrict__ in_g, const float* __restrict__ in_b,
    const short* __restrict__ w0h, const short* __restrict__ w0l,
    const short* __restrict__ w1h, const short* __restrict__ w1l,
    const short* __restrict__ w2h, const short* __restrict__ w2l,
    const short* __restrict__ ls0h, const short* __restrict__ ls0l,
    const float* __restrict__ ls0b,
    const short* __restrict__ ls1h, const short* __restrict__ ls1l,
    const float* __restrict__ ls1b,
    const short* __restrict__ linh, const short* __restrict__ linl,
    const float* __restrict__ linb,
    const short* __restrict__ ol1h, const short* __restrict__ ol1l,
    const float* __restrict__ ol1b,
    const float* __restrict__ ol2w, const float* __restrict__ ol2b,
    const float* __restrict__ on_g, const float* __restrict__ on_b,
    float* __restrict__ y){
  __shared__ __align__(16) char sm[53248];
  float* Dt    = (float*)sm;                    // [le][388]
  int*   elocal= (int*)(sm + 24832);            // [512]
  int*   lcnt  = (int*)(sm + 26880);            // [16]
  int*   loff  = lcnt + 16;                     // [17]
  int*   lcur  = loff + 17;                     // [16]
  short* T1h   = (short*)sm;                    // [16][288]
  short* T1l   = (short*)(sm + 9216);
  short* PlnL  = (short*)sm;                    // tile: [(pl*4+hc4)*1280 + node*80 + oct*16], pl in [0,2)
  float* xls   = (float*)sm;                    // [16][388]
  short* X3h   = (short*)sm;                    // [16][160]
  short* X3l   = (short*)(sm + 5120);
  float* partL = (float*)(sm + 10240);          // [4][16]
  // region B
  char*  Bb    = sm + 28160;
  int*   tmpb  = (int*)Bb;                      // [512], phase 0 only
  float4* evL  = (float4*)Bb;                   // [16] chunk scratch (phase 1)
  float* qL    = (float*)(Bb + 256);            // [16]
  int*   zsL   = (int*)(Bb + 320);              // [16]
  int*   zdL   = (int*)(Bb + 384);              // [16]
  short* attH  = (short*)(Bb + 448);            // [16][32]
  short* attL2 = (short*)(Bb + 1472);           // [16][32]
  short* tnhL  = (short*)Bb;                    // [16][160] (phase 2+)
  short* tnlL  = (short*)(Bb + 5120);
  float* NRMt  = (float*)Bb;                    // [16][388]
  short* xhL   = (short*)Bb;                    // [16][392]
  short* xlL   = (short*)(Bb + 12544);

  int t = threadIdx.x;
  int b = blockIdx.x;
  int w = t >> 6, lane = t & 63;
  int col16 = lane & 15, quad = lane >> 4;
  int bn = b*16;
  int node = t >> 5, q5 = t & 31;   // thread owns (node, h = q5*4 .. q5*4+3)

  // ---------------- phase 0: counting-sort this block's bucket by node
  int ecnt = bcnt[b]; if (ecnt > 512) ecnt = 512;
  if (t < 16){ lcnt[t] = 0; lcur[t] = 0; }
  __syncthreads();
  for (int j = t; j < ecnt; j += 512){
    int val = bucket[b*512 + j];
    tmpb[j] = val;
    atomicAdd(&lcnt[val & 15], 1);
  }
  __syncthreads();
  if (t == 0){
    int a = 0;
    #pragma unroll
    for (int i=0;i<16;++i){ loff[i] = a; a += lcnt[i]; }
    loff[16] = a;
  }
  __syncthreads();
  for (int j = t; j < ecnt; j += 512){
    int val = tmpb[j];
    int nd = val & 15;
    int p = loff[nd] + atomicAdd(&lcur[nd], 1);
    elocal[p] = val >> 4;
  }
  __syncthreads();
  int etot = loff[16];
  int e0n = loff[node], e1n = loff[node+1];

  // ---------------- phase 1: edge chunks (RBF prologue + D-stage MFMA + accumulate)
  float pv[10][4];
  #pragma unroll
  for (int p=0;p<10;++p)
    #pragma unroll
    for (int i=0;i<4;++i) pv[p][i]=0.f;

  const float* dbp[3] = {db1, db2, db3};
  for (int c0 = 0; c0 < etot; c0 += 16){
    // 1a: edge scalars (16 threads), chunk scratch in B
    if (t < 16){
      int j = c0 + t; if (j >= etot) j = etot - 1;
      int e = elocal[j];
      int s = ei[e], tt2 = ei[NE + e];
      float dx = pos[3*s+0] - pos[3*tt2+0];
      float dy = pos[3*s+1] - pos[3*tt2+1];
      float dz = pos[3*s+2] - pos[3*tt2+2];
      float d = sqrtf(dx*dx + dy*dy + dz*dz);
      float denom = (s==tt2) ? 1.0f : d;
      float cut = 0.5f*(cosf(d*F_PIC) + 1.0f);
      evL[t] = make_float4(dx/denom, dy/denom, dz/denom, cut);
      qL[t] = expf(-F_ALPHA*d);
      zsL[t] = zA[s];
      zdL[t] = zA[tt2];
    }
    __syncthreads();
    // 1b: RBF (1 per thread: 512 = 16 edges x 32 r)
    {
      int le = t >> 5, r = t & 31;
      float m = (float)(D_START + r*D_STEP);
      float u = qL[le] - m;
      float a = evL[le].w * expf(-F_BETA*u*u);
      short hh, ll; split_bf(a, hh, ll);
      attH[le*32 + r]  = hh;
      attL2[le*32 + r] = ll;
    }
    __syncthreads();
    // 1c: D-stage MFMA (A-fragments from LDS); wave w covers cols w*48..+47
    bf16x8 ah = *(const bf16x8*)(attH  + col16*32 + quad*8);
    bf16x8 al = *(const bf16x8*)(attL2 + col16*32 + quad*8);
    f32x4 dacc[3];
    #pragma unroll
    for (int nt=0;nt<3;++nt) dacc[nt] = (f32x4){0.f,0.f,0.f,0.f};
    #pragma unroll
    for (int nt=0;nt<3;++nt){
      int col = w*48 + nt*16 + col16;
      int g = col >> 7, cg = col & 127;
      bf16x8 wh = *(const bf16x8*)(dwh + g*4096 + cg*32 + quad*8);
      bf16x8 wl = *(const bf16x8*)(dwl + g*4096 + cg*32 + quad*8);
      dacc[nt] = __builtin_amdgcn_mfma_f32_16x16x32_bf16(ah, wh, dacc[nt], 0,0,0);
      dacc[nt] = __builtin_amdgcn_mfma_f32_16x16x32_bf16(ah, wl, dacc[nt], 0,0,0);
      dacc[nt] = __builtin_amdgcn_mfma_f32_16x16x32_bf16(al, wh, dacc[nt], 0,0,0);
    }
    #pragma unroll
    for (int nt=0;nt<3;++nt){
      int col = w*48 + nt*16 + col16;
      int g = col >> 7;
      float bb = dbp[g][col & 127];
      #pragma unroll
      for (int r=0;r<4;++r)
        Dt[(quad*4+r)*388 + col] = dacc[nt][r] + bb;
    }
    __syncthreads();
    // 1d: accumulate this chunk's edges into pv (thread = (node, 4 h))
    int jlo = e0n > c0 ? e0n : c0;
    int jhi0 = c0 + 16; if (jhi0 > etot) jhi0 = etot;
    int jhi = e1n < jhi0 ? e1n : jhi0;
    int h0 = q5*4;
    for (int j = jlo; j < jhi; ++j){
      int le = j - c0;
      float4 evv = evL[le];
      int zs = zsL[le], zd = zdL[le];
      const float* pz = PZ + zs*128 + h0;
      const float* qz = QZ + zd*128 + h0;
      const float* dr = Dt + le*388 + h0;
      float vx = evv.x, vy = evv.y, vz = evv.z, cut = evv.w;
      float t3v = (vx*vx + vy*vy + vz*vz)*(1.0f/3.0f);
      #pragma unroll
      for (int i=0;i<4;++i){
        float C = cut * (pz[i] + qz[i]);
        float d1 = dr[i], d2 = dr[128+i], d3 = dr[256+i];
        pv[0][i] += d1*C;
        float wa = d2*C;
        pv[1][i] += wa*vx; pv[2][i] += wa*vy; pv[3][i] += wa*vz;
        float ws = d3*C;
        pv[4][i] += ws*(vx*vx - t3v);
        pv[5][i] += ws*(vy*vy - t3v);
        pv[6][i] += ws*(vz*vz - t3v);
        pv[7][i] += ws*(vx*vy);
        pv[8][i] += ws*(vx*vz);
        pv[9][i] += ws*(vy*vz);
      }
    }
    __syncthreads();
  }

  // ---------------- phase 2: tensor_norm + layernorm(128) -> tnorm (B)
  // node = 32 contiguous lanes within a wave-half; shfl_xor o<32 stays in-half
  {
    float tnv[4];
    float s8 = 0.f;
    #pragma unroll
    for (int i=0;i<4;++i){
      float x = 3.f*pv[0][i]*pv[0][i]
              + 2.f*(pv[1][i]*pv[1][i]+pv[2][i]*pv[2][i]+pv[3][i]*pv[3][i])
              + (pv[4][i]*pv[4][i]+pv[5][i]*pv[5][i]+pv[6][i]*pv[6][i])
              + 2.f*(pv[7][i]*pv[7][i]+pv[8][i]*pv[8][i]+pv[9][i]*pv[9][i]);
      tnv[i] = x; s8 += x;
    }
    #pragma unroll
    for (int o=16;o;o>>=1) s8 += __shfl_xor(s8, o, 64);
    float mean = s8*(1.0f/128.0f);
    float vq = 0.f;
    #pragma unroll
    for (int i=0;i<4;++i){ float d = tnv[i]-mean; vq += d*d; }
    #pragma unroll
    for (int o=16;o;o>>=1) vq += __shfl_xor(vq, o, 64);
    float rstd = 1.0f/sqrtf(vq*(1.0f/128.0f) + 1e-5f);
    #pragma unroll
    for (int i=0;i<4;++i){
      int h = q5*4 + i;
      float val = (tnv[i]-mean)*rstd*in_g[h] + in_b[h];
      short hh, ll; split_bf(val, hh, ll);
      tnhL[node*160 + h] = hh;
      tnlL[node*160 + h] = ll;
    }
  }
  __syncthreads();   // tnorm visible to all

  // ---------------- phase 3: nrm MLP (tnorm -> 256 -> 384); T1 in A, NRM in B
  {
    f32x4 macc[2];
    #pragma unroll
    for (int nt=0;nt<2;++nt) macc[nt] = (f32x4){0.f,0.f,0.f,0.f};
    #pragma unroll
    for (int kc=0; kc<4; ++kc){
      bf16x8 tah = *(const bf16x8*)(tnhL + col16*160 + kc*32 + quad*8);
      bf16x8 tal = *(const bf16x8*)(tnlL + col16*160 + kc*32 + quad*8);
      #pragma unroll
      for (int nt=0;nt<2;++nt){
        int n = w*32 + nt*16 + col16;
        bf16x8 wh = *(const bf16x8*)(ls0h + n*128 + kc*32 + quad*8);
        bf16x8 wl = *(const bf16x8*)(ls0l + n*128 + kc*32 + quad*8);
        macc[nt] = __builtin_amdgcn_mfma_f32_16x16x32_bf16(tah, wh, macc[nt], 0,0,0);
        macc[nt] = __builtin_amdgcn_mfma_f32_16x16x32_bf16(tah, wl, macc[nt], 0,0,0);
        macc[nt] = __builtin_amdgcn_mfma_f32_16x16x32_bf16(tal, wh, macc[nt], 0,0,0);
      }
    }
    // T1 writes go to A (Dt dead)
    #pragma unroll
    for (int nt=0;nt<2;++nt){
      int n = w*32 + nt*16 + col16;
      float bb = ls0b[n];
      #pragma unroll
      for (int r=0;r<4;++r){
        float v = siluf(macc[nt][r] + bb);
        short hh, ll; split_bf(v, hh, ll);
        T1h[(quad*4+r)*288 + n] = hh;
        T1l[(quad*4+r)*288 + n] = ll;
      }
    }
    __syncthreads();
    f32x4 nacc[3];
    #pragma unroll
    for (int nt=0;nt<3;++nt) nacc[nt] = (f32x4){0.f,0.f,0.f,0.f};
    #pragma unroll
    for (int kc=0; kc<8; ++kc){
      bf16x8 tah = *(const bf16x8*)(T1h + col16*288 + kc*32 + quad*8);
      bf16x8 tal = *(const bf16x8*)(T1l + col16*288 + kc*32 + quad*8);
      #pragma unroll
      for (int nt=0;nt<3;++nt){
        int n = w*48 + nt*16 + col16;
        bf16x8 wh = *(const bf16x8*)(ls1h + n*256 + kc*32 + quad*8);
        bf16x8 wl = *(const bf16x8*)(ls1l + n*256 + kc*32 + quad*8);
        nacc[nt] = __builtin_amdgcn_mfma_f32_16x16x32_bf16(tah, wh, nacc[nt], 0,0,0);
        nacc[nt] = __builtin_amdgcn_mfma_f32_16x16x32_bf16(tah, wl, nacc[nt], 0,0,0);
        nacc[nt] = __builtin_amdgcn_mfma_f32_16x16x32_bf16(tal, wh, nacc[nt], 0,0,0);
      }
    }
    __syncthreads();   // T1 + tnorm reads done; NRM overwrites B
    #pragma unroll
    for (int nt=0;nt<3;++nt){
      int n = w*48 + nt*16 + col16;
      float bb = ls1b[n];
      #pragma unroll
      for (int r=0;r<4;++r)
        NRMt[(quad*4+r)*388 + n] = siluf(nacc[nt][r] + bb);
    }
  }

  // ---------------- phase 4: mix einsum, 5 passes of 2 planes (tile @0,
  // 20480 B <= region A); wave covers 16 kout; retire per plane into xI/xA/xS
  const short* wgh[3] = {w0h, w1h, w2h};
  const short* wgl[3] = {w0l, w1l, w2l};
  float xI[4], xA[4], xS[4];
  #pragma unroll
  for (int r=0;r<4;++r){ xI[r]=0.f; xA[r]=0.f; xS[r]=0.f; }
  #pragma unroll
  for (int pass=0; pass<5; ++pass){
    const int pbase = pass*2;
    __syncthreads();   // prior tile/T1 readers done; pass 0 covers NRM write
    #pragma unroll
    for (int pl=0; pl<2; ++pl){
      short* dst = PlnL + (pl*4 + (q5>>3))*1280 + node*80 + ((q5>>1)&3)*16 + (q5&1)*4;
      #pragma unroll
      for (int i=0;i<4;++i){
        short hh, ll; split_bf(pv[pbase+pl][i], hh, ll);
        dst[i] = hh; dst[8+i] = ll;
      }
    }
    __syncthreads();
    f32x4 acc[2];
    #pragma unroll
    for (int pl=0;pl<2;++pl) acc[pl] = (f32x4){0.f,0.f,0.f,0.f};
    #pragma unroll
    for (int hc4=0; hc4<4; ++hc4){
      bf16x8 bh, bl;
      int curg = -1;
      #pragma unroll
      for (int pl=0; pl<2; ++pl){
        const int p = pbase + pl;
        const int g = (p==0)?0:((p<4)?1:2);
        if (g != curg){
          int row = w*16 + col16;
          bh = *(const bf16x8*)(wgh[g] + row*128 + hc4*32 + quad*8);
          bl = *(const bf16x8*)(wgl[g] + row*128 + hc4*32 + quad*8);
          curg = g;
        }
        const short* ab = PlnL + (pl*4 + hc4)*1280 + col16*80 + quad*16;
        bf16x8 ah = *(const bf16x8*)(ab);
        bf16x8 al = *(const bf16x8*)(ab + 8);
        acc[pl] = __builtin_amdgcn_mfma_f32_16x16x32_bf16(ah, bh, acc[pl], 0,0,0);
        acc[pl] = __builtin_amdgcn_mfma_f32_16x16x32_bf16(ah, bl, acc[pl], 0,0,0);
        acc[pl] = __builtin_amdgcn_mfma_f32_16x16x32_bf16(al, bh, acc[pl], 0,0,0);
      }
    }
    // retire this pass's planes (reads NRM in B)
    #pragma unroll
    for (int pl=0; pl<2; ++pl){
      const int p = pbase + pl;
      const int sel = (p==0)?0:((p<4)?1:2);
      int k = w*16 + col16;
      #pragma unroll
      for (int r=0; r<4; ++r){
        int nloc = quad*4 + r;
        float n = NRMt[nloc*388 + 3*k + sel];
        float v = acc[pl][r]*n;
        if (p==0)      xI[r]  = 3.f*v*v;
        else if (p<4)  xA[r] += 2.f*v*v;
        else if (p<7)  xS[r] += v*v;
        else           xS[r] += 2.f*v*v;
      }
    }
  }
  __syncthreads();   // tile dead

  // ---------------- phase 5: write xls (A) + layernorm(384) -> xh/xl (B)
  {
    int k = w*16 + col16;
    #pragma unroll
    for (int r=0; r<4; ++r){
      int nloc = quad*4 + r;
      xls[nloc*388 + k]       = xI[r];
      xls[nloc*388 + 128 + k] = xA[r];
      xls[nloc*388 + 256 + k] = xS[r];
    }
  }
  __syncthreads();
  {
    float vv[12];
    float s = 0.f;
    #pragma unroll
    for (int i=0;i<12;++i){ vv[i] = xls[node*388 + q5*12 + i]; s += vv[i]; }
    #pragma unroll
    for (int o=16;o;o>>=1) s += __shfl_xor(s, o, 64);
    float mean = s*(1.0f/384.0f);
    float qsum = 0.f;
    #pragma unroll
    for (int i=0;i<12;++i){ float d = vv[i]-mean; qsum += d*d; }
    #pragma unroll
    for (int o=16;o;o>>=1) qsum += __shfl_xor(qsum, o, 64);
    float rstd = 1.0f/sqrtf(qsum*(1.0f/384.0f) + 1e-5f);
    #pragma unroll
    for (int i=0;i<12;++i){
      int c = q5*12 + i;
      float val = (vv[i]-mean)*rstd*on_g[c] + on_b[c];
      short hh, ll; split_bf(val, hh, ll);
      xhL[node*392 + c] = hh;
      xlL[node*392 + c] = ll;
    }
  }
  __syncthreads();

  // ---------------- phase 6: lin GEMM (384 -> 128) + silu -> X3 (A)
  {
    f32x4 lacc = (f32x4){0.f,0.f,0.f,0.f};
    int n = w*16 + col16;
    #pragma unroll
    for (int kc=0; kc<12; ++kc){
      bf16x8 xah = *(const bf16x8*)(xhL + col16*392 + kc*32 + quad*8);
      bf16x8 xal = *(const bf16x8*)(xlL + col16*392 + kc*32 + quad*8);
      bf16x8 wh = *(const bf16x8*)(linh + n*384 + kc*32 + quad*8);
      bf16x8 wl = *(const bf16x8*)(linl + n*384 + kc*32 + quad*8);
      lacc = __builtin_amdgcn_mfma_f32_16x16x32_bf16(xah, wh, lacc, 0,0,0);
      lacc = __builtin_amdgcn_mfma_f32_16x16x32_bf16(xah, wl, lacc, 0,0,0);
      lacc = __builtin_amdgcn_mfma_f32_16x16x32_bf16(xal, wh, lacc, 0,0,0);
    }
    __syncthreads();   // xls/xh reads done; X3 overwrites A
    float bb = linb[n];
    #pragma unroll
    for (int r=0;r<4;++r){
      float v = siluf(lacc[r] + bb);
      short hh, ll; split_bf(v, hh, ll);
      X3h[(quad*4+r)*160 + n] = hh;
      X3l[(quad*4+r)*160 + n] = ll;
    }
    __syncthreads();
  }

  // ---------------- phase 7: head (128 -> 64 -> 1); waves 0-3 only
  if (w < 4){
    f32x4 hacc = (f32x4){0.f,0.f,0.f,0.f};
    int n = w*16 + col16;
    #pragma unroll
    for (int kc=0; kc<4; ++kc){
      bf16x8 xah = *(const bf16x8*)(X3h + col16*160 + kc*32 + quad*8);
      bf16x8 xal = *(const bf16x8*)(X3l + col16*160 + kc*32 + quad*8);
      bf16x8 wh = *(const bf16x8*)(ol1h + n*128 + kc*32 + quad*8);
      bf16x8 wl = *(const bf16x8*)(ol1l + n*128 + kc*32 + quad*8);
      hacc = __builtin_amdgcn_mfma_f32_16x16x32_bf16(xah, wh, hacc, 0,0,0);
      hacc = __builtin_amdgcn_mfma_f32_16x16x32_bf16(xah, wl, hacc, 0,0,0);
      hacc = __builtin_amdgcn_mfma_f32_16x16x32_bf16(xal, wh, hacc, 0,0,0);
    }
    float b1 = ol1b[n], w2 = ol2w[n];
    #pragma unroll
    for (int r=0;r<4;++r){
      float v = siluf(hacc[r] + b1) * w2;
      #pragma unroll
      for (int o=8;o;o>>=1) v += __shfl_xor(v, o, 64);
      if (col16 == 0) partL[w*16 + quad*4 + r] = v;
    }
  }
  __syncthreads();
  if (t < 16)
    y[bn + t] = partL[t] + partL[16+t] + partL[32+t] + partL[48+t] + ol2b[0];
}

extern "C" void kernel_launch(void* const* d_in, const int* in_sizes, int n_in,
                              void* d_out, int out_size, void* d_ws, size_t ws_size,
                              hipStream_t stream) {
  const int*   z      = (const int*)d_in[0];
  const float* pos    = (const float*)d_in[1];
  const int*   ei     = (const int*)d_in[3];   // int64 in reference -> int32 from harness
  const float* emb_w  = (const float*)d_in[4];
  const float* emb2_w = (const float*)d_in[5];
  const float* emb2_b = (const float*)d_in[6];
  const float* dp1_w  = (const float*)d_in[7];
  const float* dp1_b  = (const float*)d_in[8];
  const float* dp2_w  = (const float*)d_in[9];
  const float* dp2_b  = (const float*)d_in[10];
  const float* dp3_w  = (const float*)d_in[11];
  const float* dp3_b  = (const float*)d_in[12];
  const float* lt0_w  = (const float*)d_in[13];
  const float* lt1_w  = (const float*)d_in[14];
  const float* lt2_w  = (const float*)d_in[15];
  const float* ls0_w  = (const float*)d_in[16];
  const float* ls0_b  = (const float*)d_in[17];
  const float* ls1_w  = (const float*)d_in[18];
  const float* ls1_b  = (const float*)d_in[19];
  const float* in_g   = (const float*)d_in[20];
  const float* in_b   = (const float*)d_in[21];
  const float* lin_w  = (const float*)d_in[22];
  const float* lin_b  = (const float*)d_in[23];
  const float* on_g   = (const float*)d_in[24];
  const float* on_b   = (const float*)d_in[25];
  const float* ol1_w  = (const float*)d_in[26];
  const float* ol1_b  = (const float*)d_in[27];
  const float* ol2_w  = (const float*)d_in[28];
  const float* ol2_b  = (const float*)d_in[29];
  float* out = (float*)d_out;

  const size_t NEED = 4u*1024u*1024u;
  char* wsb = (char*)d_ws;
  if (ws_size < NEED){
    void* p = nullptr;
    hipGetSymbolAddress(&p, HIP_SYMBOL(g_pool));
    wsb = (char*)p;
  }
  size_t off = 0;
  auto alloc = [&](size_t bytes)->void*{
    void* p = wsb + off;
    off = (off + bytes + 255) & ~(size_t)255;
    return p;
  };
  float* PZ      = (float*)alloc(128*128*4);
  float* QZ      = (float*)alloc(128*128*4);
  int*   bcnt    = (int*)  alloc(1024*4);
  int*   bucket  = (int*)  alloc((size_t)1024*512*4);
  short* dwh     = (short*)alloc(3*128*32*2);
  short* dwl     = (short*)alloc(3*128*32*2);
  short* ls0h    = (short*)alloc(256*128*2);
  short* ls0l    = (short*)alloc(256*128*2);
  short* ls1h    = (short*)alloc(384*256*2);
  short* ls1l    = (short*)alloc(384*256*2);
  short* linh    = (short*)alloc(128*384*2);
  short* linl    = (short*)alloc(128*384*2);
  short* lt0h    = (short*)alloc(128*128*2);
  short* lt0l    = (short*)alloc(128*128*2);
  short* lt1h    = (short*)alloc(128*128*2);
  short* lt1l    = (short*)alloc(128*128*2);
  short* lt2h    = (short*)alloc(128*128*2);
  short* lt2l    = (short*)alloc(128*128*2);
  short* ol1h    = (short*)alloc(64*128*2);
  short* ol1l    = (short*)alloc(64*128*2);

  hipMemsetAsync(bcnt, 0, 1024*4, stream);

  k_prep<<<1296, 256, 0, stream>>>(ei, pos, emb_w, emb2_w, emb2_b,
                                   ls0_w, ls1_w, lin_w, lt0_w, lt1_w, lt2_w,
                                   dp1_w, dp2_w, dp3_w, ol1_w,
                                   PZ, QZ, bcnt, bucket,
                                   ls0h, ls0l, ls1h, ls1l, linh, linl,
                                   lt0h, lt0l, lt1h, lt1l, lt2h, lt2l,
                                   dwh, dwl, ol1h, ol1l);
  k_mega<<<NN/16, 512, 0, stream>>>(bcnt, bucket, ei, pos, z,
                                    dwh, dwl, dp1_b, dp2_b, dp3_b,
                                    PZ, QZ, in_g, in_b,
                                    lt0h, lt0l, lt1h, lt1l, lt2h, lt2l,
                                    ls0h, ls0l, ls0_b, ls1h, ls1l, ls1_b,
                                    linh, linl, lin_b, ol1h, ol1l, ol1_b,
                                    ol2_w, ol2_b, on_g, on_b, out);
}

// Round 18
// 263.026 us; speedup vs baseline: 1.0485x; 1.0485x over previous
//
#include <hip/hip_runtime.h>
#include <math.h>

#define NN 16384
#define NE 65536
#define HH 128

// ---- constants matching the reference exactly (double, folded to f32) ----
constexpr double D_START = 0.011108996538242306;   // exp(-4.5)
constexpr double D_STEP  = (1.0 - D_START) / 31.0;
constexpr float  F_ALPHA = (float)(5.0/4.5);
constexpr double D_BB    = (2.0/32.0)*(1.0 - D_START);
constexpr float  F_BETA  = (float)(1.0/(D_BB*D_BB));
constexpr float  F_PIC   = (float)(M_PI/4.5);

// fallback scratch pool (used if ws_size too small). ~13 MB needed now.
#define POOL_BYTES (16u*1024u*1024u)
__device__ __align__(256) static char g_pool[POOL_BYTES];

typedef __attribute__((ext_vector_type(8))) short bf16x8;
typedef __attribute__((ext_vector_type(4))) float f32x4;

__device__ __forceinline__ float siluf(float x){
  return x * (1.0f/(1.0f + expf(-x)));
}
__device__ __forceinline__ short f2bf(float x){
  unsigned u = __float_as_uint(x);
  unsigned r = (u + 0x7fffu + ((u>>16)&1u)) >> 16;
  return (short)r;
}
__device__ __forceinline__ float bf2f(short h){
  return __uint_as_float(((unsigned)(unsigned short)h)<<16);
}
__device__ __forceinline__ void split_bf(float x, short& h, short& l){
  h = f2bf(x);
  l = f2bf(x - bf2f(h));
}

// =====================================================================
// PREP: one kernel, three independent block ranges:
//   [0,64)      : PZ/QZ tables (2 atom rows per block)
//   [64,1040)   : weight fp32 -> bf16 hi/lo conversion
//   [1040,1296) : per-edge distance/cutoff/RBF + bucket-by-16-node-group
// =====================================================================
__global__ __launch_bounds__(256) void k_prep(
    const int* __restrict__ ei, const float* __restrict__ pos,
    const int* __restrict__ z,
    const float* __restrict__ emb_w, const float* __restrict__ emb2_w,
    const float* __restrict__ emb2_b,
    const float* __restrict__ ls0, const float* __restrict__ ls1,
    const float* __restrict__ lin, const float* __restrict__ lt0,
    const float* __restrict__ lt1, const float* __restrict__ lt2,
    const float* __restrict__ dp1, const float* __restrict__ dp2,
    const float* __restrict__ dp3, const float* __restrict__ ol1,
    float* __restrict__ PZ, float* __restrict__ QZ,
    int* __restrict__ bcnt, int* __restrict__ bucket,
    int* __restrict__ ezs, int* __restrict__ ezd, float* __restrict__ ev,
    short* __restrict__ atth, short* __restrict__ attl,
    short* __restrict__ ls0h, short* __restrict__ ls0l,
    short* __restrict__ ls1h, short* __restrict__ ls1l,
    short* __restrict__ linh, short* __restrict__ linl,
    short* __restrict__ lt0h, short* __restrict__ lt0l,
    short* __restrict__ lt1h, short* __restrict__ lt1l,
    short* __restrict__ lt2h, short* __restrict__ lt2l,
    short* __restrict__ dwh, short* __restrict__ dwl,
    short* __restrict__ ol1h, short* __restrict__ ol1l){
  int b = blockIdx.x;
  if (b < 64){
    __shared__ float erow[2][128];
    int sub = threadIdx.x >> 7, h = threadIdx.x & 127;
    int a = b*2 + sub;
    erow[sub][h] = emb_w[a*128 + h];
    __syncthreads();
    float p = 0.f, q = 0.f;
    #pragma unroll 8
    for (int k=0;k<128;++k){
      float e = erow[sub][k];
      p += e * emb2_w[h*256 + k];
      q += e * emb2_w[h*256 + 128 + k];
    }
    PZ[a*128 + h] = p + emb2_b[h];
    QZ[a*128 + h] = q;
    return;
  }
  if (b < 1040){
    int tid = (b-64)*256 + threadIdx.x;   // 249856 total
    const float* s; short *dh, *dl; int i;
    if      (tid < 32768)  { s=ls0; dh=ls0h; dl=ls0l; i=tid; }
    else if (tid < 131072) { s=ls1; dh=ls1h; dl=ls1l; i=tid-32768; }
    else if (tid < 180224) { s=lin; dh=linh; dl=linl; i=tid-131072; }
    else if (tid < 196608) { s=lt0; dh=lt0h; dl=lt0l; i=tid-180224; }
    else if (tid < 212992) { s=lt1; dh=lt1h; dl=lt1l; i=tid-196608; }
    else if (tid < 229376) { s=lt2; dh=lt2h; dl=lt2l; i=tid-212992; }
    else if (tid < 241664) {
      int j = tid - 229376;       // [g*4096 + idx]
      int g = j >> 12, idx = j & 4095;
      s = (g==0)?dp1:((g==1)?dp2:dp3);
      short h,l; split_bf(s[idx], h, l);
      dwh[j] = h; dwl[j] = l;
      return;
    }
    else { s=ol1; dh=ol1h; dl=ol1l; i=tid-241664; }
    short h,l; split_bf(s[i], h, l);
    dh[i] = h; dl[i] = l;
    return;
  }
  {
    int e = (b-1040)*256 + threadIdx.x;
    int s = ei[e];
    int t = ei[NE + e];
    float dx = pos[3*s+0] - pos[3*t+0];
    float dy = pos[3*s+1] - pos[3*t+1];
    float dz = pos[3*s+2] - pos[3*t+2];
    float d = sqrtf(dx*dx + dy*dy + dz*dz);
    if (d < 4.5f){
      int g16 = s >> 4;
      int p = atomicAdd(&bcnt[g16], 1);
      if (p < 512) bucket[g16*512 + p] = (e<<4) | (s & 15);
      ezs[e] = z[s];
      ezd[e] = z[t];
      float denom = (s==t) ? 1.0f : d;
      ev[4*e+0] = dx/denom;
      ev[4*e+1] = dy/denom;
      ev[4*e+2] = dz/denom;
      float cut = 0.5f*(cosf(d*F_PIC) + 1.0f);
      ev[4*e+3] = cut;
      float q = expf(-F_ALPHA*d);
      #pragma unroll
      for (int r=0;r<32;++r){
        float m = (float)(D_START + r*D_STEP);
        float u = q - m;
        float a = cut * expf(-F_BETA*u*u);
        short hh, ll; split_bf(a, hh, ll);
        atth[32*e + r] = hh;
        attl[32*e + r] = ll;
      }
    }
  }
}

// =====================================================================
// MEGA: 512 threads (8 waves), 16 nodes/block; thread owns (node, 4 h)
// -> pv[10][4]=40 regs. N-dims split over 8 waves. LDS 76288 B.
// Region A [0, 51200): Dt[16][388]f32 + elocal/counts | T1 h/l | mix tile
//                       5pl x 4hc4 x 2560 B = 51200 B | xls f32 |
//                       X3 h/l + head partials
// Region B [51200, 76288): tmpb | tnorm h/l | NRM f32 | xh/xl
// __launch_bounds__(512,4): reg cap 128 total; measured VGPR 64, no spill.
// Session-best configuration (R15: 266.5 us total, k_mega 150 us).
// =====================================================================
__global__ __launch_bounds__(512, 4) void k_mega(
    const int* __restrict__ bcnt, const int* __restrict__ bucket,
    const int* __restrict__ ezs, const int* __restrict__ ezd,
    const float* __restrict__ ev,
    const short* __restrict__ atth, const short* __restrict__ attl,
    const short* __restrict__ dwh, const short* __restrict__ dwl,
    const float* __restrict__ db1, const float* __restrict__ db2,
    const float* __restrict__ db3,
    const float* __restrict__ PZ, const float* __restrict__ QZ,
    const float* __restrict__ in_g, const float* __restrict__ in_b,
    const short* __restrict__ w0h, const short* __restrict__ w0l,
    const short* __restrict__ w1h, const short* __restrict__ w1l,
    const short* __restrict__ w2h, const short* __restrict__ w2l,
    const short* __restrict__ ls0h, const short* __restrict__ ls0l,
    const float* __restrict__ ls0b,
    const short* __restrict__ ls1h, const short* __restrict__ ls1l,
    const float* __restrict__ ls1b,
    const short* __restrict__ linh, const short* __restrict__ linl,
    const float* __restrict__ linb,
    const short* __restrict__ ol1h, const short* __restrict__ ol1l,
    const float* __restrict__ ol1b,
    const float* __restrict__ ol2w, const float* __restrict__ ol2b,
    const float* __restrict__ on_g, const float* __restrict__ on_b,
    float* __restrict__ y){
  __shared__ __align__(16) char sm[76288];
  float* Dt    = (float*)sm;                    // [le][388]
  int*   elocal= (int*)(sm + 24832);            // [512]
  int*   lcnt  = (int*)(sm + 26880);            // [16]
  int*   loff  = lcnt + 16;                     // [17]
  int*   lcur  = loff + 17;                     // [16]
  short* T1h   = (short*)sm;                    // [16][288]
  short* T1l   = (short*)(sm + 9216);
  short* PlnL  = (short*)sm;                    // tile: [(pl*4+hc4)*1280 + node*80 + oct*16 + hl*8 + h7]
  float* xls   = (float*)sm;                    // [16][388]
  short* X3h   = (short*)sm;                    // [16][160]
  short* X3l   = (short*)(sm + 5120);
  float* partL = (float*)(sm + 10240);          // [4][16]
  int*   tmpb  = (int*)(sm + 51200);            // [512], phase 0 only
  short* tnhL  = (short*)(sm + 51200);          // [16][160]
  short* tnlL  = (short*)(sm + 51200 + 5120);
  float* NRMt  = (float*)(sm + 51200);          // [16][388]
  short* xhL   = (short*)(sm + 51200);          // [16][392]
  short* xlL   = (short*)(sm + 51200 + 12544);

  int t = threadIdx.x;
  int b = blockIdx.x;
  int w = t >> 6, lane = t & 63;
  int col16 = lane & 15, quad = lane >> 4;
  int bn = b*16;
  int node = t >> 5, q5 = t & 31;   // thread owns (node, h = q5*4 .. q5*4+3)

  // ---------------- phase 0: counting-sort this block's bucket by node
  int ecnt = bcnt[b]; if (ecnt > 512) ecnt = 512;
  if (t < 16){ lcnt[t] = 0; lcur[t] = 0; }
  __syncthreads();
  for (int j = t; j < ecnt; j += 512){
    int val = bucket[b*512 + j];
    tmpb[j] = val;
    atomicAdd(&lcnt[val & 15], 1);
  }
  __syncthreads();
  if (t == 0){
    int a = 0;
    #pragma unroll
    for (int i=0;i<16;++i){ loff[i] = a; a += lcnt[i]; }
    loff[16] = a;
  }
  __syncthreads();
  for (int j = t; j < ecnt; j += 512){
    int val = tmpb[j];
    int nd = val & 15;
    int p = loff[nd] + atomicAdd(&lcur[nd], 1);
    elocal[p] = val >> 4;
  }
  __syncthreads();
  int etot = loff[16];
  int e0n = loff[node], e1n = loff[node+1];

  // ---------------- phase 1: edge chunks (D-stage MFMA + accumulate pv)
  float pv[10][4];
  #pragma unroll
  for (int p=0;p<10;++p)
    #pragma unroll
    for (int i=0;i<4;++i) pv[p][i]=0.f;

  const float* dbp[3] = {db1, db2, db3};
  for (int c0 = 0; c0 < etot; c0 += 16){
    int jA = c0 + col16; if (jA >= etot) jA = etot - 1;
    int eA = elocal[jA];
    bf16x8 ah = *(const bf16x8*)(atth + (size_t)eA*32 + quad*8);
    bf16x8 al = *(const bf16x8*)(attl + (size_t)eA*32 + quad*8);
    f32x4 dacc[3];
    #pragma unroll
    for (int nt=0;nt<3;++nt) dacc[nt] = (f32x4){0.f,0.f,0.f,0.f};
    #pragma unroll
    for (int nt=0;nt<3;++nt){
      int col = w*48 + nt*16 + col16;
      int g = col >> 7, cg = col & 127;
      bf16x8 wh = *(const bf16x8*)(dwh + g*4096 + cg*32 + quad*8);
      bf16x8 wl = *(const bf16x8*)(dwl + g*4096 + cg*32 + quad*8);
      dacc[nt] = __builtin_amdgcn_mfma_f32_16x16x32_bf16(ah, wh, dacc[nt], 0,0,0);
      dacc[nt] = __builtin_amdgcn_mfma_f32_16x16x32_bf16(ah, wl, dacc[nt], 0,0,0);
      dacc[nt] = __builtin_amdgcn_mfma_f32_16x16x32_bf16(al, wh, dacc[nt], 0,0,0);
    }
    #pragma unroll
    for (int nt=0;nt<3;++nt){
      int col = w*48 + nt*16 + col16;
      int g = col >> 7;
      float bb = dbp[g][col & 127];
      #pragma unroll
      for (int r=0;r<4;++r)
        Dt[(quad*4+r)*388 + col] = dacc[nt][r] + bb;
    }
    __syncthreads();
    int jlo = e0n > c0 ? e0n : c0;
    int jhi0 = c0 + 16; if (jhi0 > etot) jhi0 = etot;
    int jhi = e1n < jhi0 ? e1n : jhi0;
    int h0 = q5*4;
    for (int j = jlo; j < jhi; ++j){
      int le = j - c0;
      int e = elocal[j];
      float4 evv = *(const float4*)(ev + 4*e);
      int zs = ezs[e], zd = ezd[e];
      const float* pz = PZ + zs*128 + h0;
      const float* qz = QZ + zd*128 + h0;
      const float* dr = Dt + le*388 + h0;
      float vx = evv.x, vy = evv.y, vz = evv.z, cut = evv.w;
      float t3v = (vx*vx + vy*vy + vz*vz)*(1.0f/3.0f);
      #pragma unroll
      for (int i=0;i<4;++i){
        float C = cut * (pz[i] + qz[i]);
        float d1 = dr[i], d2 = dr[128+i], d3 = dr[256+i];
        pv[0][i] += d1*C;
        float wa = d2*C;
        pv[1][i] += wa*vx; pv[2][i] += wa*vy; pv[3][i] += wa*vz;
        float ws = d3*C;
        pv[4][i] += ws*(vx*vx - t3v);
        pv[5][i] += ws*(vy*vy - t3v);
        pv[6][i] += ws*(vz*vz - t3v);
        pv[7][i] += ws*(vx*vy);
        pv[8][i] += ws*(vx*vz);
        pv[9][i] += ws*(vy*vz);
      }
    }
    __syncthreads();
  }

  // ---------------- phase 2: tensor_norm + layernorm(128) -> tnorm (B)
  // node = 32 contiguous lanes within a wave-half; shfl_xor o<32 stays in-half
  {
    float tnv[4];
    float s8 = 0.f;
    #pragma unroll
    for (int i=0;i<4;++i){
      float x = 3.f*pv[0][i]*pv[0][i]
              + 2.f*(pv[1][i]*pv[1][i]+pv[2][i]*pv[2][i]+pv[3][i]*pv[3][i])
              + (pv[4][i]*pv[4][i]+pv[5][i]*pv[5][i]+pv[6][i]*pv[6][i])
              + 2.f*(pv[7][i]*pv[7][i]+pv[8][i]*pv[8][i]+pv[9][i]*pv[9][i]);
      tnv[i] = x; s8 += x;
    }
    #pragma unroll
    for (int o=16;o;o>>=1) s8 += __shfl_xor(s8, o, 64);
    float mean = s8*(1.0f/128.0f);
    float vq = 0.f;
    #pragma unroll
    for (int i=0;i<4;++i){ float d = tnv[i]-mean; vq += d*d; }
    #pragma unroll
    for (int o=16;o;o>>=1) vq += __shfl_xor(vq, o, 64);
    float rstd = 1.0f/sqrtf(vq*(1.0f/128.0f) + 1e-5f);
    #pragma unroll
    for (int i=0;i<4;++i){
      int h = q5*4 + i;
      float val = (tnv[i]-mean)*rstd*in_g[h] + in_b[h];
      short hh, ll; split_bf(val, hh, ll);
      tnhL[node*160 + h] = hh;
      tnlL[node*160 + h] = ll;
    }
  }
  __syncthreads();   // tnorm visible to all

  // ---------------- phase 3: nrm MLP (tnorm -> 256 -> 384); T1 in A, NRM in B
  {
    f32x4 macc[2];
    #pragma unroll
    for (int nt=0;nt<2;++nt) macc[nt] = (f32x4){0.f,0.f,0.f,0.f};
    #pragma unroll
    for (int kc=0; kc<4; ++kc){
      bf16x8 tah = *(const bf16x8*)(tnhL + col16*160 + kc*32 + quad*8);
      bf16x8 tal = *(const bf16x8*)(tnlL + col16*160 + kc*32 + quad*8);
      #pragma unroll
      for (int nt=0;nt<2;++nt){
        int n = w*32 + nt*16 + col16;
        bf16x8 wh = *(const bf16x8*)(ls0h + n*128 + kc*32 + quad*8);
        bf16x8 wl = *(const bf16x8*)(ls0l + n*128 + kc*32 + quad*8);
        macc[nt] = __builtin_amdgcn_mfma_f32_16x16x32_bf16(tah, wh, macc[nt], 0,0,0);
        macc[nt] = __builtin_amdgcn_mfma_f32_16x16x32_bf16(tah, wl, macc[nt], 0,0,0);
        macc[nt] = __builtin_amdgcn_mfma_f32_16x16x32_bf16(tal, wh, macc[nt], 0,0,0);
      }
    }
    // T1 writes go to A (Dt dead); all waves already past phase-1 barrier
    #pragma unroll
    for (int nt=0;nt<2;++nt){
      int n = w*32 + nt*16 + col16;
      float bb = ls0b[n];
      #pragma unroll
      for (int r=0;r<4;++r){
        float v = siluf(macc[nt][r] + bb);
        short hh, ll; split_bf(v, hh, ll);
        T1h[(quad*4+r)*288 + n] = hh;
        T1l[(quad*4+r)*288 + n] = ll;
      }
    }
    __syncthreads();
    f32x4 nacc[3];
    #pragma unroll
    for (int nt=0;nt<3;++nt) nacc[nt] = (f32x4){0.f,0.f,0.f,0.f};
    #pragma unroll
    for (int kc=0; kc<8; ++kc){
      bf16x8 tah = *(const bf16x8*)(T1h + col16*288 + kc*32 + quad*8);
      bf16x8 tal = *(const bf16x8*)(T1l + col16*288 + kc*32 + quad*8);
      #pragma unroll
      for (int nt=0;nt<3;++nt){
        int n = w*48 + nt*16 + col16;
        bf16x8 wh = *(const bf16x8*)(ls1h + n*256 + kc*32 + quad*8);
        bf16x8 wl = *(const bf16x8*)(ls1l + n*256 + kc*32 + quad*8);
        nacc[nt] = __builtin_amdgcn_mfma_f32_16x16x32_bf16(tah, wh, nacc[nt], 0,0,0);
        nacc[nt] = __builtin_amdgcn_mfma_f32_16x16x32_bf16(tah, wl, nacc[nt], 0,0,0);
        nacc[nt] = __builtin_amdgcn_mfma_f32_16x16x32_bf16(tal, wh, nacc[nt], 0,0,0);
      }
    }
    __syncthreads();   // T1 + tnorm reads done; NRM overwrites B
    #pragma unroll
    for (int nt=0;nt<3;++nt){
      int n = w*48 + nt*16 + col16;
      float bb = ls1b[n];
      #pragma unroll
      for (int r=0;r<4;++r)
        NRMt[(quad*4+r)*388 + n] = siluf(nacc[nt][r] + bb);
    }
  }

  // ---------------- phase 4: mix einsum, 2 passes of 5 planes (tile @0,
  // 51200 B); wave covers 16 kout (w*16); retire per plane into xI/xA/xS
  const short* wgh[3] = {w0h, w1h, w2h};
  const short* wgl[3] = {w0l, w1l, w2l};
  float xI[4], xA[4], xS[4];
  #pragma unroll
  for (int r=0;r<4;++r){ xI[r]=0.f; xA[r]=0.f; xS[r]=0.f; }
  #pragma unroll
  for (int pass=0; pass<2; ++pass){
    const int pbase = pass*5;
    __syncthreads();   // prior tile/T1 readers done; pass 0 covers NRM write
    #pragma unroll
    for (int pl=0; pl<5; ++pl){
      // thread owns h = q5*4..+3: hc4 = q5>>3, oct = (q5>>1)&3, h7 = (q5&1)*4+i
      short* dst = PlnL + (pl*4 + (q5>>3))*1280 + node*80 + ((q5>>1)&3)*16 + (q5&1)*4;
      #pragma unroll
      for (int i=0;i<4;++i){
        short hh, ll; split_bf(pv[pbase+pl][i], hh, ll);
        dst[i] = hh; dst[8+i] = ll;
      }
    }
    __syncthreads();
    f32x4 acc[5];
    #pragma unroll
    for (int pl=0;pl<5;++pl) acc[pl] = (f32x4){0.f,0.f,0.f,0.f};
    #pragma unroll
    for (int hc4=0; hc4<4; ++hc4){
      bf16x8 bh, bl;
      int curg = -1;
      #pragma unroll
      for (int pl=0; pl<5; ++pl){
        const int p = pbase + pl;
        const int g = (p==0)?0:((p<4)?1:2);
        if (g != curg){
          int row = w*16 + col16;
          bh = *(const bf16x8*)(wgh[g] + row*128 + hc4*32 + quad*8);
          bl = *(const bf16x8*)(wgl[g] + row*128 + hc4*32 + quad*8);
          curg = g;
        }
        const short* ab = PlnL + (pl*4 + hc4)*1280 + col16*80 + quad*16;
        bf16x8 ah = *(const bf16x8*)(ab);
        bf16x8 al = *(const bf16x8*)(ab + 8);
        acc[pl] = __builtin_amdgcn_mfma_f32_16x16x32_bf16(ah, bh, acc[pl], 0,0,0);
        acc[pl] = __builtin_amdgcn_mfma_f32_16x16x32_bf16(ah, bl, acc[pl], 0,0,0);
        acc[pl] = __builtin_amdgcn_mfma_f32_16x16x32_bf16(al, bh, acc[pl], 0,0,0);
      }
    }
    // retire this pass's planes (reads NRM in B)
    #pragma unroll
    for (int pl=0; pl<5; ++pl){
      const int p = pbase + pl;
      const int sel = (p==0)?0:((p<4)?1:2);
      int k = w*16 + col16;
      #pragma unroll
      for (int r=0; r<4; ++r){
        int nloc = quad*4 + r;
        float n = NRMt[nloc*388 + 3*k + sel];
        float v = acc[pl][r]*n;
        if (p==0)      xI[r]  = 3.f*v*v;
        else if (p<4)  xA[r] += 2.f*v*v;
        else if (p<7)  xS[r] += v*v;
        else           xS[r] += 2.f*v*v;
      }
    }
  }
  __syncthreads();   // tile dead

  // ---------------- phase 5: write xls (A) + layernorm(384) -> xh/xl (B)
  {
    int k = w*16 + col16;
    #pragma unroll
    for (int r=0; r<4; ++r){
      int nloc = quad*4 + r;
      xls[nloc*388 + k]       = xI[r];
      xls[nloc*388 + 128 + k] = xA[r];
      xls[nloc*388 + 256 + k] = xS[r];
    }
  }
  __syncthreads();
  {
    float vv[12];
    float s = 0.f;
    #pragma unroll
    for (int i=0;i<12;++i){ vv[i] = xls[node*388 + q5*12 + i]; s += vv[i]; }
    #pragma unroll
    for (int o=16;o;o>>=1) s += __shfl_xor(s, o, 64);
    float mean = s*(1.0f/384.0f);
    float qsum = 0.f;
    #pragma unroll
    for (int i=0;i<12;++i){ float d = vv[i]-mean; qsum += d*d; }
    #pragma unroll
    for (int o=16;o;o>>=1) qsum += __shfl_xor(qsum, o, 64);
    float rstd = 1.0f/sqrtf(qsum*(1.0f/384.0f) + 1e-5f);
    #pragma unroll
    for (int i=0;i<12;++i){
      int c = q5*12 + i;
      float val = (vv[i]-mean)*rstd*on_g[c] + on_b[c];
      short hh, ll; split_bf(val, hh, ll);
      xhL[node*392 + c] = hh;
      xlL[node*392 + c] = ll;
    }
  }
  __syncthreads();

  // ---------------- phase 6: lin GEMM (384 -> 128) + silu -> X3 (A)
  {
    f32x4 lacc = (f32x4){0.f,0.f,0.f,0.f};
    int n = w*16 + col16;
    #pragma unroll
    for (int kc=0; kc<12; ++kc){
      bf16x8 xah = *(const bf16x8*)(xhL + col16*392 + kc*32 + quad*8);
      bf16x8 xal = *(const bf16x8*)(xlL + col16*392 + kc*32 + quad*8);
      bf16x8 wh = *(const bf16x8*)(linh + n*384 + kc*32 + quad*8);
      bf16x8 wl = *(const bf16x8*)(linl + n*384 + kc*32 + quad*8);
      lacc = __builtin_amdgcn_mfma_f32_16x16x32_bf16(xah, wh, lacc, 0,0,0);
      lacc = __builtin_amdgcn_mfma_f32_16x16x32_bf16(xah, wl, lacc, 0,0,0);
      lacc = __builtin_amdgcn_mfma_f32_16x16x32_bf16(xal, wh, lacc, 0,0,0);
    }
    __syncthreads();   // xls/xh reads done; X3 overwrites A
    float bb = linb[n];
    #pragma unroll
    for (int r=0;r<4;++r){
      float v = siluf(lacc[r] + bb);
      short hh, ll; split_bf(v, hh, ll);
      X3h[(quad*4+r)*160 + n] = hh;
      X3l[(quad*4+r)*160 + n] = ll;
    }
    __syncthreads();
  }

  // ---------------- phase 7: head (128 -> 64 -> 1); waves 0-3 only
  if (w < 4){
    f32x4 hacc = (f32x4){0.f,0.f,0.f,0.f};
    int n = w*16 + col16;
    #pragma unroll
    for (int kc=0; kc<4; ++kc){
      bf16x8 xah = *(const bf16x8*)(X3h + col16*160 + kc*32 + quad*8);
      bf16x8 xal = *(const bf16x8*)(X3l + col16*160 + kc*32 + quad*8);
      bf16x8 wh = *(const bf16x8*)(ol1h + n*128 + kc*32 + quad*8);
      bf16x8 wl = *(const bf16x8*)(ol1l + n*128 + kc*32 + quad*8);
      hacc = __builtin_amdgcn_mfma_f32_16x16x32_bf16(xah, wh, hacc, 0,0,0);
      hacc = __builtin_amdgcn_mfma_f32_16x16x32_bf16(xah, wl, hacc, 0,0,0);
      hacc = __builtin_amdgcn_mfma_f32_16x16x32_bf16(xal, wh, hacc, 0,0,0);
    }
    float b1 = ol1b[n], w2 = ol2w[n];
    #pragma unroll
    for (int r=0;r<4;++r){
      float v = siluf(hacc[r] + b1) * w2;
      #pragma unroll
      for (int o=8;o;o>>=1) v += __shfl_xor(v, o, 64);
      if (col16 == 0) partL[w*16 + quad*4 + r] = v;
    }
  }
  __syncthreads();
  if (t < 16)
    y[bn + t] = partL[t] + partL[16+t] + partL[32+t] + partL[48+t] + ol2b[0];
}

extern "C" void kernel_launch(void* const* d_in, const int* in_sizes, int n_in,
                              void* d_out, int out_size, void* d_ws, size_t ws_size,
                              hipStream_t stream) {
  const int*   z      = (const int*)d_in[0];
  const float* pos    = (const float*)d_in[1];
  const int*   ei     = (const int*)d_in[3];   // int64 in reference -> int32 from harness
  const float* emb_w  = (const float*)d_in[4];
  const float* emb2_w = (const float*)d_in[5];
  const float* emb2_b = (const float*)d_in[6];
  const float* dp1_w  = (const float*)d_in[7];
  const float* dp1_b  = (const float*)d_in[8];
  const float* dp2_w  = (const float*)d_in[9];
  const float* dp2_b  = (const float*)d_in[10];
  const float* dp3_w  = (const float*)d_in[11];
  const float* dp3_b  = (const float*)d_in[12];
  const float* lt0_w  = (const float*)d_in[13];
  const float* lt1_w  = (const float*)d_in[14];
  const float* lt2_w  = (const float*)d_in[15];
  const float* ls0_w  = (const float*)d_in[16];
  const float* ls0_b  = (const float*)d_in[17];
  const float* ls1_w  = (const float*)d_in[18];
  const float* ls1_b  = (const float*)d_in[19];
  const float* in_g   = (const float*)d_in[20];
  const float* in_b   = (const float*)d_in[21];
  const float* lin_w  = (const float*)d_in[22];
  const float* lin_b  = (const float*)d_in[23];
  const float* on_g   = (const float*)d_in[24];
  const float* on_b   = (const float*)d_in[25];
  const float* ol1_w  = (const float*)d_in[26];
  const float* ol1_b  = (const float*)d_in[27];
  const float* ol2_w  = (const float*)d_in[28];
  const float* ol2_b  = (const float*)d_in[29];
  float* out = (float*)d_out;

  const size_t NEED = 14u*1024u*1024u;
  char* wsb = (char*)d_ws;
  if (ws_size < NEED){
    void* p = nullptr;
    hipGetSymbolAddress(&p, HIP_SYMBOL(g_pool));
    wsb = (char*)p;
  }
  size_t off = 0;
  auto alloc = [&](size_t bytes)->void*{
    void* p = wsb + off;
    off = (off + bytes + 255) & ~(size_t)255;
    return p;
  };
  float* PZ      = (float*)alloc(128*128*4);
  float* QZ      = (float*)alloc(128*128*4);
  int*   bcnt    = (int*)  alloc(1024*4);
  int*   bucket  = (int*)  alloc((size_t)1024*512*4);
  int*   ezs     = (int*)  alloc(NE*4);
  int*   ezd     = (int*)  alloc(NE*4);
  float* ev      = (float*)alloc((size_t)NE*4*4);
  short* atth    = (short*)alloc((size_t)NE*32*2);
  short* attl    = (short*)alloc((size_t)NE*32*2);
  short* dwh     = (short*)alloc(3*128*32*2);
  short* dwl     = (short*)alloc(3*128*32*2);
  short* ls0h    = (short*)alloc(256*128*2);
  short* ls0l    = (short*)alloc(256*128*2);
  short* ls1h    = (short*)alloc(384*256*2);
  short* ls1l    = (short*)alloc(384*256*2);
  short* linh    = (short*)alloc(128*384*2);
  short* linl    = (short*)alloc(128*384*2);
  short* lt0h    = (short*)alloc(128*128*2);
  short* lt0l    = (short*)alloc(128*128*2);
  short* lt1h    = (short*)alloc(128*128*2);
  short* lt1l    = (short*)alloc(128*128*2);
  short* lt2h    = (short*)alloc(128*128*2);
  short* lt2l    = (short*)alloc(128*128*2);
  short* ol1h    = (short*)alloc(64*128*2);
  short* ol1l    = (short*)alloc(64*128*2);

  hipMemsetAsync(bcnt, 0, 1024*4, stream);

  k_prep<<<1296, 256, 0, stream>>>(ei, pos, z, emb_w, emb2_w, emb2_b,
                                   ls0_w, ls1_w, lin_w, lt0_w, lt1_w, lt2_w,
                                   dp1_w, dp2_w, dp3_w, ol1_w,
                                   PZ, QZ, bcnt, bucket, ezs, ezd, ev, atth, attl,
                                   ls0h, ls0l, ls1h, ls1l, linh, linl,
                                   lt0h, lt0l, lt1h, lt1l, lt2h, lt2l,
                                   dwh, dwl, ol1h, ol1l);
  k_mega<<<NN/16, 512, 0, stream>>>(bcnt, bucket, ezs, ezd, ev, atth, attl,
                                    dwh, dwl, dp1_b, dp2_b, dp3_b,
                                    PZ, QZ, in_g, in_b,
                                    lt0h, lt0l, lt1h, lt1l, lt2h, lt2l,
                                    ls0h, ls0l, ls0_b, ls1h, ls1l, ls1_b,
                                    linh, linl, lin_b, ol1h, ol1l, ol1_b,
                                    ol2_w, ol2_b, on_g, on_b, out);
}